// Round 7
// baseline (292.968 us; speedup 1.0000x reference)
//
#include <hip/hip_runtime.h>
#include <cstdint>

// ---------------------------------------------------------------------------
// MultiHeadAttention fwd: B=2, S=2048, D=1024, H=16, d_k=64, fp32 in/out.
//   1) fused fp32->bf16 convert (1 launch)
//   2) fused 3-way projection GEMM_bt -> head-major [B,H,S,64] bf16,
//      Q scaled by 0.125*log2(e)
//   3) flash attention, split-KV: 512 blocks x 8 waves; waves 0-3 do
//      kv[0:1024], waves 4-7 kv[1024:2048] of the same 128 q-rows; swapped
//      QK^T 32x32, per-lane softmax + defer-max, P via per-wave swizzled LDS,
//      swapped PV, reg-staged K/V (async-split), end merge. setprio on MFMA.
//   4) output projection GEMM_bt (head-major A) -> fp32 d_out
// ---------------------------------------------------------------------------

typedef float  f32x4   __attribute__((ext_vector_type(4)));
typedef float  f32x16  __attribute__((ext_vector_type(16)));
typedef __bf16 bf16x8  __attribute__((ext_vector_type(8)));
typedef unsigned short u16;
typedef u16 u16x4 __attribute__((ext_vector_type(4)));
typedef u16 u16x8 __attribute__((ext_vector_type(8)));

#define D_MODEL 1024
#define SEQ     2048
#define BATCH   2
#define NH      16
#define DKH     64
#define MTOT    (BATCH * SEQ)   // 4096
#define KVB     64
#define QBLK    128
#define HSTRIDE ((size_t)SEQ * DKH)   // elems per (b,h) head-plane

#if __has_builtin(__builtin_amdgcn_exp2f)
#define EXP2(x) __builtin_amdgcn_exp2f(x)
#else
#define EXP2(x) exp2f(x)
#endif

__device__ __forceinline__ u16 f2bf(float f) {
  uint32_t u = __builtin_bit_cast(uint32_t, f);
  u = u + 0x7fffu + ((u >> 16) & 1u);   // RNE
  return (u16)(u >> 16);
}
__device__ __forceinline__ u16 f2bf_hw(float f) {
  return __builtin_bit_cast(u16, (__bf16)f);
}

// async global->LDS, 16B/lane; dest = wave-uniform base + lane*16
__device__ __forceinline__ void gl_lds16(const void* g, void* l) {
  __builtin_amdgcn_global_load_lds(
      (__attribute__((address_space(1))) void*)(g),
      (__attribute__((address_space(3))) void*)(l), 16, 0, 0);
}

// ---------------------------------------------------------------------------
__device__ __forceinline__ void cvt_body(const float* __restrict__ in,
                                         u16* __restrict__ out, int i) {
  float4 v = reinterpret_cast<const float4*>(in)[i];
  uint32_t p0 = (uint32_t)f2bf(v.x) | ((uint32_t)f2bf(v.y) << 16);
  uint32_t p1 = (uint32_t)f2bf(v.z) | ((uint32_t)f2bf(v.w) << 16);
  reinterpret_cast<uint2*>(out)[i] = make_uint2(p0, p1);
}

// all 7 converts in one launch; NA/NW are powers of two.
__global__ __launch_bounds__(256) void cvt_all(
    const float* q, const float* k, const float* v,
    const float* w0, const float* w1, const float* w2, const float* w3,
    u16* qb, u16* kb, u16* vb, u16* o0, u16* o1, u16* o2, u16* o3) {
  const int NA = 1 << 20, NW = 1 << 18;   // quads: ACT/4, WEL/4
  int i = blockIdx.x * 256 + threadIdx.x;
  const float* src; u16* dst; int r;
  if (i < 3 * NA) {
    int s = i >> 20; r = i & (NA - 1);
    src = (s == 0) ? q : (s == 1) ? k : v;
    dst = (s == 0) ? qb : (s == 1) ? kb : vb;
  } else {
    int j = i - 3 * NA; int s = j >> 18; r = j & (NW - 1);
    src = (s == 0) ? w0 : (s == 1) ? w1 : (s == 2) ? w2 : w3;
    dst = (s == 0) ? o0 : (s == 1) ? o1 : (s == 2) ? o2 : o3;
  }
  cvt_body(src, dst, r);
}

// ---------------------------------------------------------------------------
// C[M][N] = A[M][K]*W[N][K]^T + bias, scaled. 128x128 tile, 256 thr.
// HEADA: A is head-major [B,NH,SEQ,64]; HEADC: C written head-major bf16.
template <bool BF16OUT, bool HEADA, bool HEADC>
__device__ __forceinline__ void gemm_bt_body(
    const u16* __restrict__ A, const u16* __restrict__ W,
    const float* __restrict__ bias, void* __restrict__ Cout,
    int N, int K, float scale, int bidx) {
  __shared__ u16 As[128][64];
  __shared__ u16 Bs[128][64];
  const int nbx = N / 128;
  const int bx = bidx % nbx, by = bidx / nbx;
  const int tid = threadIdx.x, wave = tid >> 6, lane = tid & 63;
  const int l15 = lane & 15, lg = lane >> 4;
  const int wr = wave >> 1, wc = wave & 1;
  f32x4 acc[4][4] = {};
  const int rA = by * 128 + (lane >> 3);
  const int rB = bx * 128 + (lane >> 3);
  const int ccol = (lane & 7) * 8;

  for (int kt = 0; kt < K; kt += 64) {
    for (int c = wave; c < 16; c += 4) {
      if (HEADA) {
        int m = rA + 8 * c;
        size_t a_off = (size_t)((m >> 11) * NH + (kt >> 6)) * HSTRIDE +
                       (size_t)(m & (SEQ - 1)) * 64 + ccol;
        gl_lds16(A + a_off, &As[8 * c][0]);
      } else {
        gl_lds16(A + (size_t)(rA + 8 * c) * K + kt + ccol, &As[8 * c][0]);
      }
      gl_lds16(W + (size_t)(rB + 8 * c) * K + kt + ccol, &Bs[8 * c][0]);
    }
    __syncthreads();
#pragma unroll
    for (int kc = 0; kc < 2; ++kc) {
      bf16x8 af[4], bw[4];
#pragma unroll
      for (int m = 0; m < 4; ++m)
        af[m] = *(const bf16x8*)&As[wr * 64 + m * 16 + l15][kc * 32 + 8 * lg];
#pragma unroll
      for (int n = 0; n < 4; ++n)
        bw[n] = *(const bf16x8*)&Bs[wc * 64 + n * 16 + l15][kc * 32 + 8 * lg];
#pragma unroll
      for (int m = 0; m < 4; ++m)
#pragma unroll
        for (int n = 0; n < 4; ++n)
          acc[m][n] = __builtin_amdgcn_mfma_f32_16x16x32_bf16(
              af[m], bw[n], acc[m][n], 0, 0, 0);
    }
    __syncthreads();
  }
#pragma unroll
  for (int n = 0; n < 4; ++n) {
    int col = bx * 128 + wc * 64 + n * 16 + l15;
    float bv = bias[col];
#pragma unroll
    for (int m = 0; m < 4; ++m) {
      int row0 = by * 128 + wr * 64 + m * 16 + 4 * lg;
#pragma unroll
      for (int j = 0; j < 4; ++j) {
        float v = (acc[m][n][j] + bv) * scale;
        int row = row0 + j;
        if (HEADC) {
          size_t off = (size_t)((row >> 11) * NH + (col >> 6)) * HSTRIDE +
                       (size_t)(row & (SEQ - 1)) * 64 + (col & 63);
          ((u16*)Cout)[off] = f2bf(v);
        } else if (BF16OUT) {
          ((u16*)Cout)[(size_t)row * N + col] = f2bf(v);
        } else {
          ((float*)Cout)[(size_t)row * N + col] = v;
        }
      }
    }
  }
}

#define SCALE_Q 0.18033688011112042f   // 0.125 * log2(e)

__global__ __launch_bounds__(256) void proj_kernel(
    const u16* qb, const u16* kb, const u16* vb,
    const u16* wq, const u16* wk, const u16* wv,
    const float* b_q, const float* b_k, const float* b_v,
    u16* Qp, u16* Kp, u16* Vp) {
  int z = blockIdx.y;
  const u16* A = (z == 0) ? qb : (z == 1) ? kb : vb;
  const u16* W = (z == 0) ? wq : (z == 1) ? wk : wv;
  const float* bi = (z == 0) ? b_q : (z == 1) ? b_k : b_v;
  u16* O = (z == 0) ? Qp : (z == 1) ? Kp : Vp;
  float scale = (z == 0) ? SCALE_Q : 1.0f;
  gemm_bt_body<true, false, true>(A, W, bi, O, D_MODEL, D_MODEL, scale,
                                  blockIdx.x);
}

__global__ __launch_bounds__(256) void oproj_kernel(
    const u16* Op, const u16* wo, const float* b_o, float* out) {
  gemm_bt_body<false, true, false>(Op, wo, b_o, out, D_MODEL, D_MODEL, 1.0f,
                                   blockIdx.x);
}

// ---------------------------------------------------------------------------
// Flash attention, split-KV. grid 512 blocks x 512 thr. bid = qt*32 + g,
// g = b*NH+h (same-head blocks share an XCD L2). Block covers 128 q-rows;
// wave w: q-group (w&3) rows [32(w&3), +32), kv half (w>>2) of 2048.
// Lane owns q = 32*(w&3) + l31; hi = lane>>5.
// All LDS layouts identical to the verified R5 mappings (chunk ^= key).
__global__ __launch_bounds__(512, 4) void attn_kernel(
    const u16* __restrict__ Qh, const u16* __restrict__ Kh,
    const u16* __restrict__ Vh, u16* __restrict__ Oh) {
  __shared__ u16 QPl[16384];     // 32KB: Q stage (16KB) -> 8x4KB P -> MrgAcc
  __shared__ u16 Ks[2][4096];    // 16KB: [half][64x64] swz -> Os epilogue
  __shared__ u16 Vt[2][4096];    // 16KB: [half][dk64 x kv64] swz -> MrgML
  const int bid = blockIdx.x;
  const int g = bid & 31, qt = bid >> 5;
  const size_t base = (size_t)g * HSTRIDE;
  const int tid = threadIdx.x, wave = tid >> 6, lane = tid & 63;
  const int l31 = lane & 31, hi = lane >> 5;
  const int qg = wave & 3, half = wave >> 2;
  const int q0 = qt * QBLK;
  const int srow = lane >> 3;
  const int scol = 8 * ((lane & 7) ^ srow);   // pre-swizzled Q source col

  // staging roles (per half: threads tid>>8 == half stage Ks/Vt[half])
  const int ht = tid & 255;
  const int kr = ht >> 2, kc4 = ht & 3;          // K: row 0..63, 32B group
  const int vp2 = ht >> 3, vd8 = (ht & 7) * 8;   // V: kv-pair 0..31, dk8
  const size_t kvbase = base + (size_t)(half * (SEQ / 2)) * 64;

  // ---- stage Q (128 x 64) via gl_lds, swizzled source ----
  for (int c = wave; c < 16; c += 8)
    gl_lds16(Qh + base + (size_t)(q0 + 8 * c + srow) * 64 + scol,
             QPl + 8 * c * 64);
  // ---- load K/V tile 0 to regs ----
  u16x8 kra, krb, va, vb;
  {
    const u16* ks = Kh + kvbase + (size_t)kr * 64 + kc4 * 16;
    kra = *(const u16x8*)ks;
    krb = *(const u16x8*)(ks + 8);
    const u16* vs = Vh + kvbase + (size_t)(2 * vp2) * 64 + vd8;
    va = *(const u16x8*)vs;
    vb = *(const u16x8*)(vs + 64);
  }
  asm volatile("s_waitcnt vmcnt(0)" ::: "memory");
  __syncthreads();                       // Q landed
#define STORE_KV()                                                         \
  {                                                                        \
    *(u16x8*)&Ks[half][kr * 64 + (((2 * kc4) ^ (kr & 7)) << 3)] = kra;     \
    *(u16x8*)&Ks[half][kr * 64 + (((2 * kc4 + 1) ^ (kr & 7)) << 3)] = krb; \
    _Pragma("unroll") for (int d = 0; d < 8; ++d) {                        \
      int dk = vd8 + d;                                                    \
      uint32_t wv = (uint32_t)va[d] | ((uint32_t)vb[d] << 16);             \
      *(uint32_t*)&Vt[half][dk * 64 + (((vp2 >> 2) ^ ((dk >> 2) & 7)) << 3) + \
                            (vp2 & 3) * 2] = wv;                           \
    }                                                                      \
  }
  STORE_KV();
  __syncthreads();                       // K/V tile 0 visible

  // ---- Q fragments: qf[kk] = Q[q=32qg+l31][16kk + 8hi + 0..7] ----
  bf16x8 qf[4];
#pragma unroll
  for (int kk = 0; kk < 4; ++kk) {
    int row = qg * 32 + l31;
    qf[kk] = *(const bf16x8*)&QPl[row * 64 + (((2 * kk + hi) ^ (row & 7)) << 3)];
  }
  __syncthreads();                       // all qf reads done before P writes
  u16* Pw = QPl + wave * 2048;           // per-wave P slice [32 q][64 kv]

  float mrow = -3e38f, lrow = 0.f;
  f32x16 acc[2] = {};
  const int NT = (SEQ / 2) / KVB;        // 16 tiles per half

  for (int kt = 0; kt < NT; ++kt) {
    if (kt + 1 < NT) {                   // issue next-tile loads (T14 split)
      const size_t kvo = kvbase + (size_t)(kt + 1) * KVB * 64;
      const u16* ks = Kh + kvo + (size_t)kr * 64 + kc4 * 16;
      kra = *(const u16x8*)ks;
      krb = *(const u16x8*)(ks + 8);
      const u16* vs = Vh + kvo + (size_t)(2 * vp2) * 64 + vd8;
      va = *(const u16x8*)vs;
      vb = *(const u16x8*)(vs + 64);
    }
    // ---- QK^T (swapped): s[t][r] = S[kv=32t+crow(r,hi)][q=l31] ----
    f32x16 s[2] = {};
    __builtin_amdgcn_s_setprio(1);
#pragma unroll
    for (int t = 0; t < 2; ++t)
#pragma unroll
      for (int kk = 0; kk < 4; ++kk) {
        int row = t * 32 + l31;
        bf16x8 kf = *(const bf16x8*)&Ks[half][row * 64 +
                                              (((2 * kk + hi) ^ (row & 7)) << 3)];
        s[t] = __builtin_amdgcn_mfma_f32_32x32x16_bf16(kf, qf[kk], s[t], 0, 0, 0);
      }
    __builtin_amdgcn_s_setprio(0);
    // ---- online softmax (base-2), per-lane; pair-sync via shfl_xor 32 ----
    float mx[16];
#pragma unroll
    for (int r = 0; r < 16; ++r) mx[r] = fmaxf(s[0][r], s[1][r]);
#pragma unroll
    for (int st2 = 8; st2 >= 1; st2 >>= 1)
#pragma unroll
      for (int r = 0; r < st2; ++r) mx[r] = fmaxf(mx[r], mx[r + st2]);
    float mtile = fmaxf(mx[0], __shfl_xor(mx[0], 32, 64));
    // defer-max (T13): rescale only when tile max grows past THR=8
    if (mtile > mrow + 8.0f) {
      float corr = EXP2(mrow - mtile);
      mrow = mtile;
      lrow *= corr;
#pragma unroll
      for (int nd = 0; nd < 2; ++nd)
#pragma unroll
        for (int r = 0; r < 16; ++r) acc[nd][r] *= corr;
    }
    float sm0 = 0.f, sm1 = 0.f, sm2 = 0.f, sm3 = 0.f;
#pragma unroll
    for (int t = 0; t < 2; ++t)
#pragma unroll
      for (int r = 0; r < 16; r += 4) {
        float p0 = EXP2(s[t][r] - mrow);
        float p1 = EXP2(s[t][r + 1] - mrow);
        float p2 = EXP2(s[t][r + 2] - mrow);
        float p3 = EXP2(s[t][r + 3] - mrow);
        s[t][r] = p0; s[t][r + 1] = p1; s[t][r + 2] = p2; s[t][r + 3] = p3;
        sm0 += p0; sm1 += p1; sm2 += p2; sm3 += p3;
      }
    float psum = (sm0 + sm1) + (sm2 + sm3);
    lrow += psum + __shfl_xor(psum, 32, 64);

    // ---- P -> per-wave LDS (swizzled): row q, chunk (4t+b2)^(q&7), +4hi ----
#pragma unroll
    for (int t = 0; t < 2; ++t)
#pragma unroll
      for (int b2 = 0; b2 < 4; ++b2) {
        u16x4 pk = {f2bf_hw(s[t][4 * b2]), f2bf_hw(s[t][4 * b2 + 1]),
                    f2bf_hw(s[t][4 * b2 + 2]), f2bf_hw(s[t][4 * b2 + 3])};
        *(u16x4*)&Pw[l31 * 64 + (((4 * t + b2) ^ (l31 & 7)) << 3) + 4 * hi] = pk;
      }
    // ---- PV (swapped): acc[nd] += V^T x P ----
    __builtin_amdgcn_s_setprio(1);
#pragma unroll
    for (int ks2 = 0; ks2 < 4; ++ks2) {
      bf16x8 pf =
          *(const bf16x8*)&Pw[l31 * 64 + (((2 * ks2 + hi) ^ (l31 & 7)) << 3)];
#pragma unroll
      for (int nd = 0; nd < 2; ++nd) {
        int dkr = nd * 32 + l31;
        bf16x8 vf = *(const bf16x8*)&Vt[half][dkr * 64 +
                        (((2 * ks2 + hi) ^ ((l31 >> 2) & 7)) << 3)];
        acc[nd] =
            __builtin_amdgcn_mfma_f32_32x32x16_bf16(vf, pf, acc[nd], 0, 0, 0);
      }
    }
    __builtin_amdgcn_s_setprio(0);
    __syncthreads();                     // all reads of Ks/Vt[half] done
    if (kt + 1 < NT) STORE_KV();
    __syncthreads();                     // next tile visible
  }

  // ---- split-KV merge: upper waves publish (acc, m, l); lower combine ----
  float* MA = (float*)QPl;               // 4 slices x 2048 f32 (32KB)
  float* ML = (float*)Vt;                // 4 x 128 f32 (2KB)
  if (wave >= 4) {
    int u = wave - 4;
#pragma unroll
    for (int j = 0; j < 8; ++j) {
      f32x4 qd = {acc[j >> 2][4 * (j & 3)], acc[j >> 2][4 * (j & 3) + 1],
                  acc[j >> 2][4 * (j & 3) + 2], acc[j >> 2][4 * (j & 3) + 3]};
      *(f32x4*)&MA[u * 2048 + lane * 32 + ((j ^ (lane & 7)) << 2)] = qd;
    }
    ML[u * 128 + lane * 2] = mrow;
    ML[u * 128 + lane * 2 + 1] = lrow;
  }
  __syncthreads();
  u16* Os = &Ks[0][0];                   // [128][64] swizzled O stage (16KB)
  if (wave < 4) {
    float mb = ML[wave * 128 + lane * 2];
    float lb = ML[wave * 128 + lane * 2 + 1];
    float m2 = fmaxf(mrow, mb);
    float ca = EXP2(mrow - m2), cb = EXP2(mb - m2);
    lrow = lrow * ca + lb * cb;
#pragma unroll
    for (int j = 0; j < 8; ++j) {
      f32x4 qd = *(const f32x4*)&MA[wave * 2048 + lane * 32 +
                                    ((j ^ (lane & 7)) << 2)];
#pragma unroll
      for (int m = 0; m < 4; ++m)
        acc[j >> 2][4 * (j & 3) + m] =
            acc[j >> 2][4 * (j & 3) + m] * ca + qd[m] * cb;
    }
    float rinv = 1.0f / lrow;
    int row = wave * 32 + l31;
#pragma unroll
    for (int nd = 0; nd < 2; ++nd)
#pragma unroll
      for (int b2 = 0; b2 < 4; ++b2) {
        u16x4 ok = {f2bf_hw(acc[nd][4 * b2] * rinv),
                    f2bf_hw(acc[nd][4 * b2 + 1] * rinv),
                    f2bf_hw(acc[nd][4 * b2 + 2] * rinv),
                    f2bf_hw(acc[nd][4 * b2 + 3] * rinv)};
        *(u16x4*)&Os[row * 64 + (((4 * nd + b2) ^ (row & 7)) << 3) + 4 * hi] =
            ok;
      }
  }
  __syncthreads();
  {  // coalesced store: 4 threads/row x 2 chunks x 8 u16
    const int row = tid >> 2, cq = tid & 3;
    u16* gp = (u16*)(Oh + base + (size_t)(q0 + row) * 64);
#pragma unroll
    for (int e = 0; e < 2; ++e) {
      int c = 2 * cq + e;
      *(u16x8*)(gp + c * 8) =
          *(const u16x8*)&Os[row * 64 + ((c ^ (row & 7)) << 3)];
    }
  }
}

// ---------------------------------------------------------------------------
extern "C" void kernel_launch(void* const* d_in, const int* in_sizes, int n_in,
                              void* d_out, int out_size, void* d_ws,
                              size_t ws_size, hipStream_t stream) {
  (void)in_sizes; (void)n_in; (void)out_size; (void)ws_size;
  const float* q   = (const float*)d_in[0];
  const float* k   = (const float*)d_in[1];
  const float* v   = (const float*)d_in[2];
  const float* w_q = (const float*)d_in[3];
  const float* b_q = (const float*)d_in[4];
  const float* w_k = (const float*)d_in[5];
  const float* b_k = (const float*)d_in[6];
  const float* w_v = (const float*)d_in[7];
  const float* b_v = (const float*)d_in[8];
  const float* w_o = (const float*)d_in[9];
  const float* b_o = (const float*)d_in[10];
  float* out = (float*)d_out;

  const size_t ACT = (size_t)MTOT * D_MODEL;     // 4M elems
  const size_t WEL = (size_t)D_MODEL * D_MODEL;  // 1M elems
  u16* qb  = (u16*)d_ws;
  u16* kb  = qb + ACT;
  u16* vb  = kb + ACT;
  u16* wqb = vb + ACT;
  u16* wkb = wqb + WEL;
  u16* wvb = wkb + WEL;
  u16* wob = wvb + WEL;
  u16* Qp  = wob + WEL;   // head-major [B,NH,SEQ,64]
  u16* Kp  = Qp + ACT;
  u16* Vp  = Kp + ACT;
  u16* Op  = Vp + ACT;

  const int nq = (int)((3 * ACT + 4 * WEL) / 4);   // total quads
  cvt_all<<<nq / 256, 256, 0, stream>>>(q, k, v, w_q, w_k, w_v, w_o,
                                        qb, kb, vb, wqb, wkb, wvb, wob);

  proj_kernel<<<dim3((MTOT / 128) * (D_MODEL / 128), 3), 256, 0, stream>>>(
      qb, kb, vb, wqb, wkb, wvb, b_q, b_k, b_v, Qp, Kp, Vp);

  attn_kernel<<<dim3(BATCH * NH * (SEQ / QBLK)), 512, 0, stream>>>(Qp, Kp, Vp,
                                                                   Op);

  oproj_kernel<<<dim3((MTOT / 128) * (D_MODEL / 128)), 256, 0, stream>>>(
      Op, wob, b_o, out);
}

// Round 8
// 243.875 us; speedup vs baseline: 1.2013x; 1.2013x over previous
//
#include <hip/hip_runtime.h>
#include <cstdint>

// ---------------------------------------------------------------------------
// MultiHeadAttention fwd: B=2, S=2048, D=1024, H=16, d_k=64, fp32 in/out.
//   1) fused fp32->bf16 convert (1 launch)
//   2) fused 3-way projection GEMM_bt -> head-major [B,H,S,64] bf16,
//      Q scaled by 0.125*log2(e)
//   3) flash attention (R6 structure, verified): 256 blocks x 8 waves x
//      256 q-rows, swapped QK^T 32x32, per-lane softmax, P via per-wave
//      swizzled LDS, swapped PV. NEW: 128 kv rows per barrier pair
//      (2x 64-row sub-tiles), defer-max (T13), setprio (T5).
//   4) output projection GEMM_bt (head-major A) -> fp32 d_out
// ---------------------------------------------------------------------------

typedef float  f32x4   __attribute__((ext_vector_type(4)));
typedef float  f32x16  __attribute__((ext_vector_type(16)));
typedef __bf16 bf16x8  __attribute__((ext_vector_type(8)));
typedef unsigned short u16;
typedef u16 u16x4 __attribute__((ext_vector_type(4)));
typedef u16 u16x8 __attribute__((ext_vector_type(8)));

#define D_MODEL 1024
#define SEQ     2048
#define BATCH   2
#define NH      16
#define DKH     64
#define MTOT    (BATCH * SEQ)   // 4096
#define QBLK    256
#define HSTRIDE ((size_t)SEQ * DKH)   // elems per (b,h) head-plane

#if __has_builtin(__builtin_amdgcn_exp2f)
#define EXP2(x) __builtin_amdgcn_exp2f(x)
#else
#define EXP2(x) exp2f(x)
#endif

__device__ __forceinline__ u16 f2bf(float f) {
  uint32_t u = __builtin_bit_cast(uint32_t, f);
  u = u + 0x7fffu + ((u >> 16) & 1u);   // RNE
  return (u16)(u >> 16);
}
__device__ __forceinline__ u16 f2bf_hw(float f) {
  return __builtin_bit_cast(u16, (__bf16)f);
}

// async global->LDS, 16B/lane; dest = wave-uniform base + lane*16
__device__ __forceinline__ void gl_lds16(const void* g, void* l) {
  __builtin_amdgcn_global_load_lds(
      (__attribute__((address_space(1))) void*)(g),
      (__attribute__((address_space(3))) void*)(l), 16, 0, 0);
}

// ---------------------------------------------------------------------------
__device__ __forceinline__ void cvt_body(const float* __restrict__ in,
                                         u16* __restrict__ out, int i) {
  float4 v = reinterpret_cast<const float4*>(in)[i];
  uint32_t p0 = (uint32_t)f2bf(v.x) | ((uint32_t)f2bf(v.y) << 16);
  uint32_t p1 = (uint32_t)f2bf(v.z) | ((uint32_t)f2bf(v.w) << 16);
  reinterpret_cast<uint2*>(out)[i] = make_uint2(p0, p1);
}

// all 7 converts in one launch; NA/NW are powers of two.
__global__ __launch_bounds__(256) void cvt_all(
    const float* q, const float* k, const float* v,
    const float* w0, const float* w1, const float* w2, const float* w3,
    u16* qb, u16* kb, u16* vb, u16* o0, u16* o1, u16* o2, u16* o3) {
  const int NA = 1 << 20, NW = 1 << 18;   // quads: ACT/4, WEL/4
  int i = blockIdx.x * 256 + threadIdx.x;
  const float* src; u16* dst; int r;
  if (i < 3 * NA) {
    int s = i >> 20; r = i & (NA - 1);
    src = (s == 0) ? q : (s == 1) ? k : v;
    dst = (s == 0) ? qb : (s == 1) ? kb : vb;
  } else {
    int j = i - 3 * NA; int s = j >> 18; r = j & (NW - 1);
    src = (s == 0) ? w0 : (s == 1) ? w1 : (s == 2) ? w2 : w3;
    dst = (s == 0) ? o0 : (s == 1) ? o1 : (s == 2) ? o2 : o3;
  }
  cvt_body(src, dst, r);
}

// ---------------------------------------------------------------------------
// C[M][N] = A[M][K]*W[N][K]^T + bias, scaled. 128x128 tile, 256 thr.
// HEADA: A is head-major [B,NH,SEQ,64]; HEADC: C written head-major bf16.
template <bool BF16OUT, bool HEADA, bool HEADC>
__device__ __forceinline__ void gemm_bt_body(
    const u16* __restrict__ A, const u16* __restrict__ W,
    const float* __restrict__ bias, void* __restrict__ Cout,
    int N, int K, float scale, int bidx) {
  __shared__ u16 As[128][64];
  __shared__ u16 Bs[128][64];
  const int nbx = N / 128;
  const int bx = bidx % nbx, by = bidx / nbx;
  const int tid = threadIdx.x, wave = tid >> 6, lane = tid & 63;
  const int l15 = lane & 15, lg = lane >> 4;
  const int wr = wave >> 1, wc = wave & 1;
  f32x4 acc[4][4] = {};
  const int rA = by * 128 + (lane >> 3);
  const int rB = bx * 128 + (lane >> 3);
  const int ccol = (lane & 7) * 8;

  for (int kt = 0; kt < K; kt += 64) {
    for (int c = wave; c < 16; c += 4) {
      if (HEADA) {
        int m = rA + 8 * c;
        size_t a_off = (size_t)((m >> 11) * NH + (kt >> 6)) * HSTRIDE +
                       (size_t)(m & (SEQ - 1)) * 64 + ccol;
        gl_lds16(A + a_off, &As[8 * c][0]);
      } else {
        gl_lds16(A + (size_t)(rA + 8 * c) * K + kt + ccol, &As[8 * c][0]);
      }
      gl_lds16(W + (size_t)(rB + 8 * c) * K + kt + ccol, &Bs[8 * c][0]);
    }
    __syncthreads();
#pragma unroll
    for (int kc = 0; kc < 2; ++kc) {
      bf16x8 af[4], bw[4];
#pragma unroll
      for (int m = 0; m < 4; ++m)
        af[m] = *(const bf16x8*)&As[wr * 64 + m * 16 + l15][kc * 32 + 8 * lg];
#pragma unroll
      for (int n = 0; n < 4; ++n)
        bw[n] = *(const bf16x8*)&Bs[wc * 64 + n * 16 + l15][kc * 32 + 8 * lg];
#pragma unroll
      for (int m = 0; m < 4; ++m)
#pragma unroll
        for (int n = 0; n < 4; ++n)
          acc[m][n] = __builtin_amdgcn_mfma_f32_16x16x32_bf16(
              af[m], bw[n], acc[m][n], 0, 0, 0);
    }
    __syncthreads();
  }
#pragma unroll
  for (int n = 0; n < 4; ++n) {
    int col = bx * 128 + wc * 64 + n * 16 + l15;
    float bv = bias[col];
#pragma unroll
    for (int m = 0; m < 4; ++m) {
      int row0 = by * 128 + wr * 64 + m * 16 + 4 * lg;
#pragma unroll
      for (int j = 0; j < 4; ++j) {
        float v = (acc[m][n][j] + bv) * scale;
        int row = row0 + j;
        if (HEADC) {
          size_t off = (size_t)((row >> 11) * NH + (col >> 6)) * HSTRIDE +
                       (size_t)(row & (SEQ - 1)) * 64 + (col & 63);
          ((u16*)Cout)[off] = f2bf(v);
        } else if (BF16OUT) {
          ((u16*)Cout)[(size_t)row * N + col] = f2bf(v);
        } else {
          ((float*)Cout)[(size_t)row * N + col] = v;
        }
      }
    }
  }
}

#define SCALE_Q 0.18033688011112042f   // 0.125 * log2(e)

__global__ __launch_bounds__(256) void proj_kernel(
    const u16* qb, const u16* kb, const u16* vb,
    const u16* wq, const u16* wk, const u16* wv,
    const float* b_q, const float* b_k, const float* b_v,
    u16* Qp, u16* Kp, u16* Vp) {
  int z = blockIdx.y;
  const u16* A = (z == 0) ? qb : (z == 1) ? kb : vb;
  const u16* W = (z == 0) ? wq : (z == 1) ? wk : wv;
  const float* bi = (z == 0) ? b_q : (z == 1) ? b_k : b_v;
  u16* O = (z == 0) ? Qp : (z == 1) ? Kp : Vp;
  float scale = (z == 0) ? SCALE_Q : 1.0f;
  gemm_bt_body<true, false, true>(A, W, bi, O, D_MODEL, D_MODEL, scale,
                                  blockIdx.x);
}

__global__ __launch_bounds__(256) void oproj_kernel(
    const u16* Op, const u16* wo, const float* b_o, float* out) {
  gemm_bt_body<false, true, false>(Op, wo, b_o, out, D_MODEL, D_MODEL, 1.0f,
                                   blockIdx.x);
}

// ---------------------------------------------------------------------------
// Flash attention (R6-verified structure + 2 sub-tiles per barrier pair).
// grid 256 blocks x 512 thr. bid = qt*32 + g, g = b*NH+h (g%8 = XCD). Wave w
// owns q-rows [32w,32w+32): its QPl slice is Q-stage -> P buffer -> O-stage.
// Lane owns q = 32*wave + l31; hi = lane>>5.
// QK^T D-layout: s[t][r] = S[kv=32t+crow(r,hi)][q], crow=(r&3)+8*(r>>2)+4*hi.
__global__ __launch_bounds__(512, 2) void attn_kernel(
    const u16* __restrict__ Qh, const u16* __restrict__ Kh,
    const u16* __restrict__ Vh, u16* __restrict__ Oh) {
  __shared__ u16 QPl[QBLK * 64];       // 32KB: Q stage -> per-wave P -> Os
  __shared__ u16 Ks[2][2][64 * 64];    // 32KB: [buf][sub], chunk ^= (row&7)
  __shared__ u16 Vt[2][2][64 * 64];    // 32KB: [buf][sub] V^T, chunk ^= ((dk>>2)&7)
  const int bid = blockIdx.x;
  const int g = bid & 31, qt = bid >> 5;
  const size_t base = (size_t)g * HSTRIDE;
  const int tid = threadIdx.x, wave = tid >> 6, lane = tid & 63;
  const int l31 = lane & 31, hi = lane >> 5;
  const int q0 = qt * QBLK;
  const int srow = lane >> 3;
  const int scol = 8 * ((lane & 7) ^ srow);   // pre-swizzled source col

  // ---- stage Q (256x64) ----
  for (int c = wave; c < 32; c += 8)
    gl_lds16(Qh + base + (size_t)(q0 + 8 * c + srow) * 64 + scol,
             QPl + 8 * c * 64);
  // ---- stage K tile 0 (both subs), load V tile 0 to regs ----
  gl_lds16(Kh + base + (size_t)(8 * wave + srow) * 64 + scol,
           &Ks[0][0][8 * wave * 64]);
  gl_lds16(Kh + base + 4096 + (size_t)(8 * wave + srow) * 64 + scol,
           &Ks[0][1][8 * wave * 64]);
  const int vp = tid >> 4, vq = tid & 15;   // kv-pair 0..31, dk-quad 0..15
  u16x4 va, vb, vc, vd;
  {
    const u16* vs = Vh + base + (size_t)(2 * vp) * 64 + vq * 4;
    va = *(const u16x4*)vs;
    vb = *(const u16x4*)(vs + 64);
    vc = *(const u16x4*)(vs + 4096);
    vd = *(const u16x4*)(vs + 4096 + 64);
  }
  asm volatile("s_waitcnt vmcnt(0)" ::: "memory");
  __syncthreads();
  // write V tile 0 (transposed, packed pairs), both subs
#define STORE_V(BUF, SUB, RA, RB)                                             \
  {                                                                           \
    _Pragma("unroll") for (int j = 0; j < 4; ++j) {                           \
      int dk = vq * 4 + j;                                                    \
      uint32_t wv = (uint32_t)RA[j] | ((uint32_t)RB[j] << 16);                \
      *(uint32_t*)&Vt[BUF][SUB][dk * 64 + (((vp >> 2) ^ (vq & 7)) << 3) +     \
                               (vp & 3) * 2] = wv;                            \
    }                                                                         \
  }
  STORE_V(0, 0, va, vb);
  STORE_V(0, 1, vc, vd);
  __syncthreads();

  // ---- Q fragments: qf[kk] = Q[q=32w+l31][16kk + 8hi + 0..7] ----
  bf16x8 qf[4];
#pragma unroll
  for (int kk = 0; kk < 4; ++kk) {
    int row = wave * 32 + l31;
    qf[kk] = *(const bf16x8*)&QPl[row * 64 + (((2 * kk + hi) ^ (row & 7)) << 3)];
  }
  // per-wave P buffer overlays this wave's own Q rows (now consumed);
  // qf ds_reads precede P ds_writes in same-wave program order -> safe.
  u16* Pw = QPl + wave * 32 * 64;   // [32 q][64 kv], chunk ^= (q&7)

  float mrow = -3e38f, lrow = 0.f;
  f32x16 acc[2] = {};
  const int NT = SEQ / 128;   // 16 iterations, 128 kv rows each

  for (int kt = 0; kt < NT; ++kt) {
    const int cur = kt & 1, nxt = cur ^ 1;
    if (kt + 1 < NT) {   // issue next-tile loads: K->LDS(nxt), V->regs
      const size_t kv0 = base + (size_t)(kt + 1) * 128 * 64;
      gl_lds16(Kh + kv0 + (size_t)(8 * wave + srow) * 64 + scol,
               &Ks[nxt][0][8 * wave * 64]);
      gl_lds16(Kh + kv0 + 4096 + (size_t)(8 * wave + srow) * 64 + scol,
               &Ks[nxt][1][8 * wave * 64]);
      const u16* vs = Vh + kv0 + (size_t)(2 * vp) * 64 + vq * 4;
      va = *(const u16x4*)vs;
      vb = *(const u16x4*)(vs + 64);
      vc = *(const u16x4*)(vs + 4096);
      vd = *(const u16x4*)(vs + 4096 + 64);
    }
    // ---- QK^T both subs (swapped): sX[t][r] = S[kv][q=l31] ----
    f32x16 s0[2] = {}, s1[2] = {};
    __builtin_amdgcn_s_setprio(1);
#pragma unroll
    for (int t = 0; t < 2; ++t)
#pragma unroll
      for (int kk = 0; kk < 4; ++kk) {
        int row = t * 32 + l31;
        int off = row * 64 + (((2 * kk + hi) ^ (row & 7)) << 3);
        s0[t] = __builtin_amdgcn_mfma_f32_32x32x16_bf16(
            *(const bf16x8*)&Ks[cur][0][off], qf[kk], s0[t], 0, 0, 0);
        s1[t] = __builtin_amdgcn_mfma_f32_32x32x16_bf16(
            *(const bf16x8*)&Ks[cur][1][off], qf[kk], s1[t], 0, 0, 0);
      }
    __builtin_amdgcn_s_setprio(0);
    // ---- joint online softmax (base-2), per-lane; halves via shfl_xor 32 ----
    float mx[16];
#pragma unroll
    for (int r = 0; r < 16; ++r)
      mx[r] = fmaxf(fmaxf(s0[0][r], s0[1][r]), fmaxf(s1[0][r], s1[1][r]));
#pragma unroll
    for (int st2 = 8; st2 >= 1; st2 >>= 1)
#pragma unroll
      for (int r = 0; r < st2; ++r) mx[r] = fmaxf(mx[r], mx[r + st2]);
    float mtile = fmaxf(mx[0], __shfl_xor(mx[0], 32, 64));
    // defer-max (T13): rescale only when some lane's max grew past THR=8
    if (!__all(mtile - mrow <= 8.0f)) {
      float mnew = fmaxf(mrow, mtile);
      float corr = EXP2(mrow - mnew);
      mrow = mnew;
      lrow *= corr;
#pragma unroll
      for (int nd = 0; nd < 2; ++nd)
#pragma unroll
        for (int r = 0; r < 16; ++r) acc[nd][r] *= corr;
    }
    float sma = 0.f, smb = 0.f, smc = 0.f, smd = 0.f;
#pragma unroll
    for (int t = 0; t < 2; ++t)
#pragma unroll
      for (int r = 0; r < 16; r += 4) {
        float a0 = EXP2(s0[t][r] - mrow), a1 = EXP2(s0[t][r + 1] - mrow);
        float a2 = EXP2(s0[t][r + 2] - mrow), a3 = EXP2(s0[t][r + 3] - mrow);
        s0[t][r] = a0; s0[t][r + 1] = a1; s0[t][r + 2] = a2; s0[t][r + 3] = a3;
        sma += a0; smb += a1; smc += a2; smd += a3;
        float b0 = EXP2(s1[t][r] - mrow), b1 = EXP2(s1[t][r + 1] - mrow);
        float b2 = EXP2(s1[t][r + 2] - mrow), b3 = EXP2(s1[t][r + 3] - mrow);
        s1[t][r] = b0; s1[t][r + 1] = b1; s1[t][r + 2] = b2; s1[t][r + 3] = b3;
        sma += b0; smb += b1; smc += b2; smd += b3;
      }
    float psum = (sma + smb) + (smc + smd);
    lrow += psum + __shfl_xor(psum, 32, 64);

    // ---- sub 0: P -> per-wave LDS, then PV; then sub 1 (same-wave DS order
    // guarantees PV(sub0) reads complete before P(sub1) overwrites Pw) ----
#pragma unroll
    for (int sub = 0; sub < 2; ++sub) {
      f32x16* sp = (sub == 0) ? s0 : s1;
#pragma unroll
      for (int t = 0; t < 2; ++t)
#pragma unroll
        for (int b2 = 0; b2 < 4; ++b2) {
          u16x4 pk = {f2bf_hw(sp[t][4 * b2]), f2bf_hw(sp[t][4 * b2 + 1]),
                      f2bf_hw(sp[t][4 * b2 + 2]), f2bf_hw(sp[t][4 * b2 + 3])};
          *(u16x4*)&Pw[l31 * 64 + (((4 * t + b2) ^ (l31 & 7)) << 3) + 4 * hi] =
              pk;
        }
      __builtin_amdgcn_s_setprio(1);
#pragma unroll
      for (int ks2 = 0; ks2 < 4; ++ks2) {
        bf16x8 pf =
            *(const bf16x8*)&Pw[l31 * 64 + (((2 * ks2 + hi) ^ (l31 & 7)) << 3)];
#pragma unroll
        for (int nd = 0; nd < 2; ++nd) {
          int dkr = nd * 32 + l31;
          bf16x8 vf = *(const bf16x8*)&Vt[cur][sub][dkr * 64 +
                          (((2 * ks2 + hi) ^ ((l31 >> 2) & 7)) << 3)];
          acc[nd] =
              __builtin_amdgcn_mfma_f32_32x32x16_bf16(vf, pf, acc[nd], 0, 0, 0);
        }
      }
      __builtin_amdgcn_s_setprio(0);
    }
    asm volatile("s_waitcnt vmcnt(0)" ::: "memory");
    __syncthreads();                     // reads of cur done; K[nxt] landed
    if (kt + 1 < NT) {
      STORE_V(nxt, 0, va, vb);
      STORE_V(nxt, 1, vc, vd);
    }
    __syncthreads();                     // nxt visible
  }

  // ---- epilogue: O^T regs -> LDS transpose (own wave slice) -> global ----
  float rinv = 1.0f / lrow;
  u16* Os = QPl;
  {
    int row = wave * 32 + l31;
#pragma unroll
    for (int nd = 0; nd < 2; ++nd)
#pragma unroll
      for (int b2 = 0; b2 < 4; ++b2) {
        u16x4 ok = {f2bf_hw(acc[nd][4 * b2] * rinv),
                    f2bf_hw(acc[nd][4 * b2 + 1] * rinv),
                    f2bf_hw(acc[nd][4 * b2 + 2] * rinv),
                    f2bf_hw(acc[nd][4 * b2 + 3] * rinv)};
        *(u16x4*)&Os[row * 64 + (((4 * nd + b2) ^ (row & 7)) << 3) + 4 * hi] =
            ok;
      }
  }
  __syncthreads();
  {
    const int row = tid >> 1, half = tid & 1;
    u16* gp = (u16*)(Oh + base + (size_t)(q0 + row) * 64 + half * 32);
#pragma unroll
    for (int c2 = 0; c2 < 4; ++c2) {
      int pc = (half * 4 + c2) ^ (row & 7);
      *(u16x8*)(gp + c2 * 8) = *(const u16x8*)&Os[row * 64 + pc * 8];
    }
  }
}

// ---------------------------------------------------------------------------
extern "C" void kernel_launch(void* const* d_in, const int* in_sizes, int n_in,
                              void* d_out, int out_size, void* d_ws,
                              size_t ws_size, hipStream_t stream) {
  (void)in_sizes; (void)n_in; (void)out_size; (void)ws_size;
  const float* q   = (const float*)d_in[0];
  const float* k   = (const float*)d_in[1];
  const float* v   = (const float*)d_in[2];
  const float* w_q = (const float*)d_in[3];
  const float* b_q = (const float*)d_in[4];
  const float* w_k = (const float*)d_in[5];
  const float* b_k = (const float*)d_in[6];
  const float* w_v = (const float*)d_in[7];
  const float* b_v = (const float*)d_in[8];
  const float* w_o = (const float*)d_in[9];
  const float* b_o = (const float*)d_in[10];
  float* out = (float*)d_out;

  const size_t ACT = (size_t)MTOT * D_MODEL;     // 4M elems
  const size_t WEL = (size_t)D_MODEL * D_MODEL;  // 1M elems
  u16* qb  = (u16*)d_ws;
  u16* kb  = qb + ACT;
  u16* vb  = kb + ACT;
  u16* wqb = vb + ACT;
  u16* wkb = wqb + WEL;
  u16* wvb = wkb + WEL;
  u16* wob = wvb + WEL;
  u16* Qp  = wob + WEL;   // head-major [B,NH,SEQ,64]
  u16* Kp  = Qp + ACT;
  u16* Vp  = Kp + ACT;
  u16* Op  = Vp + ACT;

  const int nq = (int)((3 * ACT + 4 * WEL) / 4);   // total quads
  cvt_all<<<nq / 256, 256, 0, stream>>>(q, k, v, w_q, w_k, w_v, w_o,
                                        qb, kb, vb, wqb, wkb, wvb, wob);

  proj_kernel<<<dim3((MTOT / 128) * (D_MODEL / 128), 3), 256, 0, stream>>>(
      qb, kb, vb, wqb, wkb, wvb, b_q, b_k, b_v, Qp, Kp, Vp);

  attn_kernel<<<dim3(BATCH * NH * (SEQ / QBLK)), 512, 0, stream>>>(Qp, Kp, Vp,
                                                                   Op);

  oproj_kernel<<<dim3((MTOT / 128) * (D_MODEL / 128)), 256, 0, stream>>>(
      Op, wob, b_o, out);
}

// Round 9
// 235.068 us; speedup vs baseline: 1.2463x; 1.0375x over previous
//
#include <hip/hip_runtime.h>
#include <cstdint>

// ---------------------------------------------------------------------------
// MultiHeadAttention fwd: B=2, S=2048, D=1024, H=16, d_k=64, fp32 in/out.
//   1) fused fp32->bf16 convert (1 launch)
//   2) fused 3-way projection GEMM_bt -> head-major [B,H,S,64] bf16,
//      Q scaled by 0.125*log2(e); XCD-chunked block swizzle
//   3) flash attention (R6/R8 structure): 256 blocks x 8 waves x 256 q-rows,
//      swapped QK^T 32x32, per-lane softmax + defer-max, P via per-wave
//      swizzled LDS, swapped PV, 128 kv rows per barrier pair.
//      NEW: conflict-free Vt key (dk + dk>>3)&7 (was 4-way on ds_read_b128).
//   4) output projection GEMM_bt (head-major A) -> fp32 d_out, XCD swizzle
// ---------------------------------------------------------------------------

typedef float  f32x4   __attribute__((ext_vector_type(4)));
typedef float  f32x16  __attribute__((ext_vector_type(16)));
typedef __bf16 bf16x8  __attribute__((ext_vector_type(8)));
typedef unsigned short u16;
typedef u16 u16x4 __attribute__((ext_vector_type(4)));
typedef u16 u16x8 __attribute__((ext_vector_type(8)));

#define D_MODEL 1024
#define SEQ     2048
#define BATCH   2
#define NH      16
#define DKH     64
#define MTOT    (BATCH * SEQ)   // 4096
#define QBLK    256
#define HSTRIDE ((size_t)SEQ * DKH)   // elems per (b,h) head-plane

#if __has_builtin(__builtin_amdgcn_exp2f)
#define EXP2(x) __builtin_amdgcn_exp2f(x)
#else
#define EXP2(x) exp2f(x)
#endif

__device__ __forceinline__ u16 f2bf(float f) {
  uint32_t u = __builtin_bit_cast(uint32_t, f);
  u = u + 0x7fffu + ((u >> 16) & 1u);   // RNE
  return (u16)(u >> 16);
}
__device__ __forceinline__ u16 f2bf_hw(float f) {
  return __builtin_bit_cast(u16, (__bf16)f);
}

// async global->LDS, 16B/lane; dest = wave-uniform base + lane*16
__device__ __forceinline__ void gl_lds16(const void* g, void* l) {
  __builtin_amdgcn_global_load_lds(
      (__attribute__((address_space(1))) void*)(g),
      (__attribute__((address_space(3))) void*)(l), 16, 0, 0);
}

// ---------------------------------------------------------------------------
__device__ __forceinline__ void cvt_body(const float* __restrict__ in,
                                         u16* __restrict__ out, int i) {
  float4 v = reinterpret_cast<const float4*>(in)[i];
  uint32_t p0 = (uint32_t)f2bf(v.x) | ((uint32_t)f2bf(v.y) << 16);
  uint32_t p1 = (uint32_t)f2bf(v.z) | ((uint32_t)f2bf(v.w) << 16);
  reinterpret_cast<uint2*>(out)[i] = make_uint2(p0, p1);
}

// all 7 converts in one launch; NA/NW are powers of two.
__global__ __launch_bounds__(256) void cvt_all(
    const float* q, const float* k, const float* v,
    const float* w0, const float* w1, const float* w2, const float* w3,
    u16* qb, u16* kb, u16* vb, u16* o0, u16* o1, u16* o2, u16* o3) {
  const int NA = 1 << 20, NW = 1 << 18;   // quads: ACT/4, WEL/4
  int i = blockIdx.x * 256 + threadIdx.x;
  const float* src; u16* dst; int r;
  if (i < 3 * NA) {
    int s = i >> 20; r = i & (NA - 1);
    src = (s == 0) ? q : (s == 1) ? k : v;
    dst = (s == 0) ? qb : (s == 1) ? kb : vb;
  } else {
    int j = i - 3 * NA; int s = j >> 18; r = j & (NW - 1);
    src = (s == 0) ? w0 : (s == 1) ? w1 : (s == 2) ? w2 : w3;
    dst = (s == 0) ? o0 : (s == 1) ? o1 : (s == 2) ? o2 : o3;
  }
  cvt_body(src, dst, r);
}

// ---------------------------------------------------------------------------
// C[M][N] = A[M][K]*W[N][K]^T + bias, scaled. 128x128 tile, 256 thr.
// HEADA: A is head-major [B,NH,SEQ,64]; HEADC: C written head-major bf16.
template <bool BF16OUT, bool HEADA, bool HEADC>
__device__ __forceinline__ void gemm_bt_body(
    const u16* __restrict__ A, const u16* __restrict__ W,
    const float* __restrict__ bias, void* __restrict__ Cout,
    int N, int K, float scale, int bidx) {
  __shared__ u16 As[128][64];
  __shared__ u16 Bs[128][64];
  const int nbx = N / 128;
  const int bx = bidx % nbx, by = bidx / nbx;
  const int tid = threadIdx.x, wave = tid >> 6, lane = tid & 63;
  const int l15 = lane & 15, lg = lane >> 4;
  const int wr = wave >> 1, wc = wave & 1;
  f32x4 acc[4][4] = {};
  const int rA = by * 128 + (lane >> 3);
  const int rB = bx * 128 + (lane >> 3);
  const int ccol = (lane & 7) * 8;

  for (int kt = 0; kt < K; kt += 64) {
    for (int c = wave; c < 16; c += 4) {
      if (HEADA) {
        int m = rA + 8 * c;
        size_t a_off = (size_t)((m >> 11) * NH + (kt >> 6)) * HSTRIDE +
                       (size_t)(m & (SEQ - 1)) * 64 + ccol;
        gl_lds16(A + a_off, &As[8 * c][0]);
      } else {
        gl_lds16(A + (size_t)(rA + 8 * c) * K + kt + ccol, &As[8 * c][0]);
      }
      gl_lds16(W + (size_t)(rB + 8 * c) * K + kt + ccol, &Bs[8 * c][0]);
    }
    __syncthreads();
#pragma unroll
    for (int kc = 0; kc < 2; ++kc) {
      bf16x8 af[4], bw[4];
#pragma unroll
      for (int m = 0; m < 4; ++m)
        af[m] = *(const bf16x8*)&As[wr * 64 + m * 16 + l15][kc * 32 + 8 * lg];
#pragma unroll
      for (int n = 0; n < 4; ++n)
        bw[n] = *(const bf16x8*)&Bs[wc * 64 + n * 16 + l15][kc * 32 + 8 * lg];
#pragma unroll
      for (int m = 0; m < 4; ++m)
#pragma unroll
        for (int n = 0; n < 4; ++n)
          acc[m][n] = __builtin_amdgcn_mfma_f32_16x16x32_bf16(
              af[m], bw[n], acc[m][n], 0, 0, 0);
    }
    __syncthreads();
  }
#pragma unroll
  for (int n = 0; n < 4; ++n) {
    int col = bx * 128 + wc * 64 + n * 16 + l15;
    float bv = bias[col];
#pragma unroll
    for (int m = 0; m < 4; ++m) {
      int row0 = by * 128 + wr * 64 + m * 16 + 4 * lg;
#pragma unroll
      for (int j = 0; j < 4; ++j) {
        float v = (acc[m][n][j] + bv) * scale;
        int row = row0 + j;
        if (HEADC) {
          size_t off = (size_t)((row >> 11) * NH + (col >> 6)) * HSTRIDE +
                       (size_t)(row & (SEQ - 1)) * 64 + (col & 63);
          ((u16*)Cout)[off] = f2bf(v);
        } else if (BF16OUT) {
          ((u16*)Cout)[(size_t)row * N + col] = f2bf(v);
        } else {
          ((float*)Cout)[(size_t)row * N + col] = v;
        }
      }
    }
  }
}

#define SCALE_Q 0.18033688011112042f   // 0.125 * log2(e)

// XCD-chunked swizzle: 256 blocks, 8 XCDs -> XCD x gets 32 consecutive
// logical tiles (4 A-row-bands x 8 W-panels): A band stays L2-local.
__device__ __forceinline__ int xcd_swz(int pid) {
  return ((pid & 7) << 5) | (pid >> 3);
}

__global__ __launch_bounds__(256) void proj_kernel(
    const u16* qb, const u16* kb, const u16* vb,
    const u16* wq, const u16* wk, const u16* wv,
    const float* b_q, const float* b_k, const float* b_v,
    u16* Qp, u16* Kp, u16* Vp) {
  int z = blockIdx.y;
  const u16* A = (z == 0) ? qb : (z == 1) ? kb : vb;
  const u16* W = (z == 0) ? wq : (z == 1) ? wk : wv;
  const float* bi = (z == 0) ? b_q : (z == 1) ? b_k : b_v;
  u16* O = (z == 0) ? Qp : (z == 1) ? Kp : Vp;
  float scale = (z == 0) ? SCALE_Q : 1.0f;
  gemm_bt_body<true, false, true>(A, W, bi, O, D_MODEL, D_MODEL, scale,
                                  xcd_swz(blockIdx.x));
}

__global__ __launch_bounds__(256) void oproj_kernel(
    const u16* Op, const u16* wo, const float* b_o, float* out) {
  gemm_bt_body<false, true, false>(Op, wo, b_o, out, D_MODEL, D_MODEL, 1.0f,
                                   xcd_swz(blockIdx.x));
}

// ---------------------------------------------------------------------------
// Flash attention (R8 structure; Vt key fixed to (dk + dk>>3)&7).
// grid 256 blocks x 512 thr. bid = qt*32 + g, g = b*NH+h (g%8 = XCD). Wave w
// owns q-rows [32w,32w+32): its QPl slice is Q-stage -> P buffer -> O-stage.
// Lane owns q = 32*wave + l31; hi = lane>>5.
// QK^T D-layout: s[t][r] = S[kv=32t+crow(r,hi)][q], crow=(r&3)+8*(r>>2)+4*hi.
__global__ __launch_bounds__(512, 2) void attn_kernel(
    const u16* __restrict__ Qh, const u16* __restrict__ Kh,
    const u16* __restrict__ Vh, u16* __restrict__ Oh) {
  __shared__ u16 QPl[QBLK * 64];       // 32KB: Q stage -> per-wave P -> Os
  __shared__ u16 Ks[2][2][64 * 64];    // 32KB: [buf][sub], chunk ^= (row&7)
  __shared__ u16 Vt[2][2][64 * 64];    // 32KB: [buf][sub] V^T, chunk ^= key(dk)
  const int bid = blockIdx.x;
  const int g = bid & 31, qt = bid >> 5;
  const size_t base = (size_t)g * HSTRIDE;
  const int tid = threadIdx.x, wave = tid >> 6, lane = tid & 63;
  const int l31 = lane & 31, hi = lane >> 5;
  const int q0 = qt * QBLK;
  const int srow = lane >> 3;
  const int scol = 8 * ((lane & 7) ^ srow);   // pre-swizzled source col

  // ---- stage Q (256x64) ----
  for (int c = wave; c < 32; c += 8)
    gl_lds16(Qh + base + (size_t)(q0 + 8 * c + srow) * 64 + scol,
             QPl + 8 * c * 64);
  // ---- stage K tile 0 (both subs), load V tile 0 to regs ----
  gl_lds16(Kh + base + (size_t)(8 * wave + srow) * 64 + scol,
           &Ks[0][0][8 * wave * 64]);
  gl_lds16(Kh + base + 4096 + (size_t)(8 * wave + srow) * 64 + scol,
           &Ks[0][1][8 * wave * 64]);
  const int vp = tid >> 4, vq = tid & 15;   // kv-pair 0..31, dk-quad 0..15
  u16x4 va, vb, vc, vd;
  {
    const u16* vs = Vh + base + (size_t)(2 * vp) * 64 + vq * 4;
    va = *(const u16x4*)vs;
    vb = *(const u16x4*)(vs + 64);
    vc = *(const u16x4*)(vs + 4096);
    vd = *(const u16x4*)(vs + 4096 + 64);
  }
  asm volatile("s_waitcnt vmcnt(0)" ::: "memory");
  __syncthreads();
  // write V tile (transposed, packed kv pairs). Row dk's chunk key
  // (dk + dk>>3)&7 is bijective within each 8-row stripe -> conflict-free
  // reads; store side stays <=2-way (chunk distinct per 8 lanes).
#define STORE_V(BUF, SUB, RA, RB)                                             \
  {                                                                           \
    _Pragma("unroll") for (int j = 0; j < 4; ++j) {                           \
      int dk = vq * 4 + j;                                                    \
      int key = (dk + (dk >> 3)) & 7;                                         \
      uint32_t wv = (uint32_t)RA[j] | ((uint32_t)RB[j] << 16);                \
      *(uint32_t*)&Vt[BUF][SUB][dk * 64 + (((vp >> 2) ^ key) << 3) +          \
                                (vp & 3) * 2] = wv;                           \
    }                                                                         \
  }
  STORE_V(0, 0, va, vb);
  STORE_V(0, 1, vc, vd);
  __syncthreads();

  // ---- Q fragments: qf[kk] = Q[q=32w+l31][16kk + 8hi + 0..7] ----
  bf16x8 qf[4];
#pragma unroll
  for (int kk = 0; kk < 4; ++kk) {
    int row = wave * 32 + l31;
    qf[kk] = *(const bf16x8*)&QPl[row * 64 + (((2 * kk + hi) ^ (row & 7)) << 3)];
  }
  // per-wave P buffer overlays this wave's own Q rows (now consumed);
  // qf ds_reads precede P ds_writes in same-wave program order -> safe.
  u16* Pw = QPl + wave * 32 * 64;   // [32 q][64 kv], chunk ^= (q&7)

  float mrow = -3e38f, lrow = 0.f;
  f32x16 acc[2] = {};
  const int NT = SEQ / 128;   // 16 iterations, 128 kv rows each

  for (int kt = 0; kt < NT; ++kt) {
    const int cur = kt & 1, nxt = cur ^ 1;
    if (kt + 1 < NT) {   // issue next-tile loads: K->LDS(nxt), V->regs
      const size_t kv0 = base + (size_t)(kt + 1) * 128 * 64;
      gl_lds16(Kh + kv0 + (size_t)(8 * wave + srow) * 64 + scol,
               &Ks[nxt][0][8 * wave * 64]);
      gl_lds16(Kh + kv0 + 4096 + (size_t)(8 * wave + srow) * 64 + scol,
               &Ks[nxt][1][8 * wave * 64]);
      const u16* vs = Vh + kv0 + (size_t)(2 * vp) * 64 + vq * 4;
      va = *(const u16x4*)vs;
      vb = *(const u16x4*)(vs + 64);
      vc = *(const u16x4*)(vs + 4096);
      vd = *(const u16x4*)(vs + 4096 + 64);
    }
    // ---- QK^T both subs (swapped): sX[t][r] = S[kv][q=l31] ----
    f32x16 s0[2] = {}, s1[2] = {};
    __builtin_amdgcn_s_setprio(1);
#pragma unroll
    for (int t = 0; t < 2; ++t)
#pragma unroll
      for (int kk = 0; kk < 4; ++kk) {
        int row = t * 32 + l31;
        int off = row * 64 + (((2 * kk + hi) ^ (row & 7)) << 3);
        s0[t] = __builtin_amdgcn_mfma_f32_32x32x16_bf16(
            *(const bf16x8*)&Ks[cur][0][off], qf[kk], s0[t], 0, 0, 0);
        s1[t] = __builtin_amdgcn_mfma_f32_32x32x16_bf16(
            *(const bf16x8*)&Ks[cur][1][off], qf[kk], s1[t], 0, 0, 0);
      }
    __builtin_amdgcn_s_setprio(0);
    // ---- joint online softmax (base-2), per-lane; halves via shfl_xor 32 ----
    float mx[16];
#pragma unroll
    for (int r = 0; r < 16; ++r)
      mx[r] = fmaxf(fmaxf(s0[0][r], s0[1][r]), fmaxf(s1[0][r], s1[1][r]));
#pragma unroll
    for (int st2 = 8; st2 >= 1; st2 >>= 1)
#pragma unroll
      for (int r = 0; r < st2; ++r) mx[r] = fmaxf(mx[r], mx[r + st2]);
    float mtile = fmaxf(mx[0], __shfl_xor(mx[0], 32, 64));
    // defer-max (T13): rescale only when some lane's max grew past THR=8
    if (!__all(mtile - mrow <= 8.0f)) {
      float mnew = fmaxf(mrow, mtile);
      float corr = EXP2(mrow - mnew);
      mrow = mnew;
      lrow *= corr;
#pragma unroll
      for (int nd = 0; nd < 2; ++nd)
#pragma unroll
        for (int r = 0; r < 16; ++r) acc[nd][r] *= corr;
    }
    float sma = 0.f, smb = 0.f, smc = 0.f, smd = 0.f;
#pragma unroll
    for (int t = 0; t < 2; ++t)
#pragma unroll
      for (int r = 0; r < 16; r += 4) {
        float a0 = EXP2(s0[t][r] - mrow), a1 = EXP2(s0[t][r + 1] - mrow);
        float a2 = EXP2(s0[t][r + 2] - mrow), a3 = EXP2(s0[t][r + 3] - mrow);
        s0[t][r] = a0; s0[t][r + 1] = a1; s0[t][r + 2] = a2; s0[t][r + 3] = a3;
        sma += a0; smb += a1; smc += a2; smd += a3;
        float b0 = EXP2(s1[t][r] - mrow), b1 = EXP2(s1[t][r + 1] - mrow);
        float b2 = EXP2(s1[t][r + 2] - mrow), b3 = EXP2(s1[t][r + 3] - mrow);
        s1[t][r] = b0; s1[t][r + 1] = b1; s1[t][r + 2] = b2; s1[t][r + 3] = b3;
        sma += b0; smb += b1; smc += b2; smd += b3;
      }
    float psum = (sma + smb) + (smc + smd);
    lrow += psum + __shfl_xor(psum, 32, 64);

    // ---- sub 0: P -> per-wave LDS, then PV; then sub 1 (same-wave DS order
    // guarantees PV(sub0) reads complete before P(sub1) overwrites Pw) ----
#pragma unroll
    for (int sub = 0; sub < 2; ++sub) {
      f32x16* sp = (sub == 0) ? s0 : s1;
#pragma unroll
      for (int t = 0; t < 2; ++t)
#pragma unroll
        for (int b2 = 0; b2 < 4; ++b2) {
          u16x4 pk = {f2bf_hw(sp[t][4 * b2]), f2bf_hw(sp[t][4 * b2 + 1]),
                      f2bf_hw(sp[t][4 * b2 + 2]), f2bf_hw(sp[t][4 * b2 + 3])};
          *(u16x4*)&Pw[l31 * 64 + (((4 * t + b2) ^ (l31 & 7)) << 3) + 4 * hi] =
              pk;
        }
      __builtin_amdgcn_s_setprio(1);
#pragma unroll
      for (int ks2 = 0; ks2 < 4; ++ks2) {
        bf16x8 pf =
            *(const bf16x8*)&Pw[l31 * 64 + (((2 * ks2 + hi) ^ (l31 & 7)) << 3)];
#pragma unroll
        for (int nd = 0; nd < 2; ++nd) {
          int dkr = nd * 32 + l31;
          int vkey = (dkr + (dkr >> 3)) & 7;
          bf16x8 vf = *(const bf16x8*)&Vt[cur][sub][dkr * 64 +
                          (((2 * ks2 + hi) ^ vkey) << 3)];
          acc[nd] =
              __builtin_amdgcn_mfma_f32_32x32x16_bf16(vf, pf, acc[nd], 0, 0, 0);
        }
      }
      __builtin_amdgcn_s_setprio(0);
    }
    asm volatile("s_waitcnt vmcnt(0)" ::: "memory");
    __syncthreads();                     // reads of cur done; K[nxt] landed
    if (kt + 1 < NT) {
      STORE_V(nxt, 0, va, vb);
      STORE_V(nxt, 1, vc, vd);
    }
    __syncthreads();                     // nxt visible
  }

  // ---- epilogue: O^T regs -> LDS transpose (own wave slice) -> global ----
  float rinv = 1.0f / lrow;
  u16* Os = QPl;
  {
    int row = wave * 32 + l31;
#pragma unroll
    for (int nd = 0; nd < 2; ++nd)
#pragma unroll
      for (int b2 = 0; b2 < 4; ++b2) {
        u16x4 ok = {f2bf_hw(acc[nd][4 * b2] * rinv),
                    f2bf_hw(acc[nd][4 * b2 + 1] * rinv),
                    f2bf_hw(acc[nd][4 * b2 + 2] * rinv),
                    f2bf_hw(acc[nd][4 * b2 + 3] * rinv)};
        *(u16x4*)&Os[row * 64 + (((4 * nd + b2) ^ (row & 7)) << 3) + 4 * hi] =
            ok;
      }
  }
  __syncthreads();
  {
    const int row = tid >> 1, half = tid & 1;
    u16* gp = (u16*)(Oh + base + (size_t)(q0 + row) * 64 + half * 32);
#pragma unroll
    for (int c2 = 0; c2 < 4; ++c2) {
      int pc = (half * 4 + c2) ^ (row & 7);
      *(u16x8*)(gp + c2 * 8) = *(const u16x8*)&Os[row * 64 + pc * 8];
    }
  }
}

// ---------------------------------------------------------------------------
extern "C" void kernel_launch(void* const* d_in, const int* in_sizes, int n_in,
                              void* d_out, int out_size, void* d_ws,
                              size_t ws_size, hipStream_t stream) {
  (void)in_sizes; (void)n_in; (void)out_size; (void)ws_size;
  const float* q   = (const float*)d_in[0];
  const float* k   = (const float*)d_in[1];
  const float* v   = (const float*)d_in[2];
  const float* w_q = (const float*)d_in[3];
  const float* b_q = (const float*)d_in[4];
  const float* w_k = (const float*)d_in[5];
  const float* b_k = (const float*)d_in[6];
  const float* w_v = (const float*)d_in[7];
  const float* b_v = (const float*)d_in[8];
  const float* w_o = (const float*)d_in[9];
  const float* b_o = (const float*)d_in[10];
  float* out = (float*)d_out;

  const size_t ACT = (size_t)MTOT * D_MODEL;     // 4M elems
  const size_t WEL = (size_t)D_MODEL * D_MODEL;  // 1M elems
  u16* qb  = (u16*)d_ws;
  u16* kb  = qb + ACT;
  u16* vb  = kb + ACT;
  u16* wqb = vb + ACT;
  u16* wkb = wqb + WEL;
  u16* wvb = wkb + WEL;
  u16* wob = wvb + WEL;
  u16* Qp  = wob + WEL;   // head-major [B,NH,SEQ,64]
  u16* Kp  = Qp + ACT;
  u16* Vp  = Kp + ACT;
  u16* Op  = Vp + ACT;

  const int nq = (int)((3 * ACT + 4 * WEL) / 4);   // total quads
  cvt_all<<<nq / 256, 256, 0, stream>>>(q, k, v, w_q, w_k, w_v, w_o,
                                        qb, kb, vb, wqb, wkb, wvb, wob);

  proj_kernel<<<dim3((MTOT / 128) * (D_MODEL / 128), 3), 256, 0, stream>>>(
      qb, kb, vb, wqb, wkb, wvb, b_q, b_k, b_v, Qp, Kp, Vp);

  attn_kernel<<<dim3(BATCH * NH * (SEQ / QBLK)), 512, 0, stream>>>(Qp, Kp, Vp,
                                                                   Op);

  oproj_kernel<<<dim3((MTOT / 128) * (D_MODEL / 128)), 256, 0, stream>>>(
      Op, wob, b_o, out);
}